// Round 16
// baseline (126.450 us; speedup 1.0000x reference)
//
#include <hip/hip_runtime.h>
#include <cstdint>
#include <cmath>

#define DEV __device__ __forceinline__

typedef float v4f __attribute__((ext_vector_type(4)));
typedef short v8s __attribute__((ext_vector_type(8)));
typedef short v4s __attribute__((ext_vector_type(4)));

// Problem constants
// x: [8,256,48,48] f32; weight: [256,256,3,3]; off_w: [18,256,3,3]; off_b:[18];
// mask_w: [9,256,3,3]; mask_b:[9]; out: [8,256,48,48] f32
static constexpr int HW    = 48 * 48;        // 2304
static constexpr int NPOS  = 8 * HW;         // 18432

DEV float bf2f(unsigned short u) {
  unsigned int v = ((unsigned int)u) << 16;
  float f; __builtin_memcpy(&f, &v, 4); return f;
}
DEV unsigned short f2bf(float f) {
  unsigned int u; __builtin_memcpy(&u, &f, 4);
  unsigned int r = (u + 0x7fffu + ((u >> 16) & 1u)) >> 16;
  return (unsigned short)r;
}

DEV void gload16(const void* g, void* l) {
  __builtin_amdgcn_global_load_lds(
      (const __attribute__((address_space(1))) unsigned int*)g,
      (__attribute__((address_space(3))) unsigned int*)l, 16, 0, 0);
}

// ---------------- prep (fused): xT transpose; Wc2+zp; wG ---------------------
// grid 1696 x 256:
//   blocks    0..1151: x NCHW f32 -> xT [b][hw][c] bf16
//   blocks 1152..1439: Wc2[32][t*256+c] bf16 (+ zp zero-page)
//   blocks 1440..1695: wG[co][k*256+c] bf16 row transpose
__global__ __launch_bounds__(256) void k_pre(const float* __restrict__ x,
                                             const float* __restrict__ off_w,
                                             const float* __restrict__ mask_w,
                                             const float* __restrict__ weight,
                                             unsigned short* __restrict__ xT,
                                             unsigned short* __restrict__ Wc2,
                                             unsigned short* __restrict__ zp,
                                             unsigned short* __restrict__ wG) {
  __shared__ float tile[64][65];
  int bid = blockIdx.x, tid = threadIdx.x;
  if (bid < 1152) {
    int ct = bid & 3; int hwt = (bid >> 2) % 36; int b = bid / 144;
    int c0 = ct * 64, hw0 = hwt * 64;
    int tl = tid & 63, tr = tid >> 6;
    const float* xb = x + (size_t)(b * 256 + c0) * 2304 + hw0;
    #pragma unroll
    for (int r = 0; r < 16; r++) {
      int cr = tr + r * 4;
      tile[cr][tl] = xb[(size_t)cr * 2304 + tl];
    }
    __syncthreads();
    unsigned short* xo = xT + ((size_t)b * 2304 + hw0) * 256 + c0;
    #pragma unroll
    for (int r = 0; r < 16; r++) {
      int hr = tr + r * 4;
      xo[(size_t)hr * 256 + tl] = f2bf(tile[tl][hr]);
    }
  } else if (bid < 1440) {
    int i = (bid - 1152) * 256 + tid;         // 288*256 = 73728 = 32*2304
    if (i < 256) zp[i] = 0;
    int o = i / 2304, col = i % 2304;
    int t = col >> 8, c = col & 255;
    float v = 0.f;
    if (o < 18)      v = off_w[(o * 256 + c) * 9 + t];
    else if (o < 27) v = mask_w[((o - 18) * 256 + c) * 9 + t];
    Wc2[i] = f2bf(v);
  } else {
    int co = bid - 1440;
    const float* wsrc = weight + (size_t)co * 2304;
    float* wrow = &tile[0][0];                // reuse 2304 floats of LDS
    for (int k = tid; k < 2304; k += 256) wrow[k] = wsrc[k];
    __syncthreads();
    unsigned short* dst = wG + (size_t)co * 2304;
    #pragma unroll
    for (int k = 0; k < 9; k++)
      dst[k * 256 + tid] = f2bf(wrow[tid * 9 + k]);
  }
}

// ---------------- offset/mask conv as MFMA GEMM ------------------------------
// S[32][NPOS] = Wc2[32][2304] * im2col(xT)[2304][NPOS], split-K by tap triple.
// grid (288, 3): BN=64, per chunk K=768 (3 taps x 256 ch), BK=64.
__global__ __launch_bounds__(256) void k_cg(const unsigned short* __restrict__ Wc2,
                                            const unsigned short* __restrict__ xT,
                                            const unsigned short* __restrict__ zp,
                                            float* __restrict__ parS) {
  __shared__ unsigned short ldsA[32 * 64];
  __shared__ unsigned short ldsB[64 * 64];
  int nt = blockIdx.x, kc = blockIdx.y;
  int n0 = nt * 64;
  int b = n0 / 2304, hw0 = n0 % 2304;         // BN=64 divides 2304: one image
  int tid = threadIdx.x, lane = tid & 63, wid = tid >> 6;
  int r = lane & 15, q = lane >> 4;
  int row0 = tid >> 3;                        // staging row (0..31)
  int sslot = (tid & 7) ^ (row0 & 7);         // pre-swizzled 16B slot

  int hwA = hw0 + row0,      hA = hwA / 48, wA = hwA % 48;   // B round 0 row
  int hwB = hw0 + row0 + 32, hB = hwB / 48, wB = hwB % 48;   // B round 1 row

  v4f acc0 = (v4f){0.f, 0.f, 0.f, 0.f};
  v4f acc1 = (v4f){0.f, 0.f, 0.f, 0.f};

  #pragma unroll
  for (int tt = 0; tt < 3; tt++) {
    int t = kc * 3 + tt;
    int dy = kc - 1, dx = tt - 1;
    int yA = hA + dy, xA = wA + dx;
    int yB = hB + dy, xB = wB + dx;
    bool vA = ((unsigned)yA < 48u) && ((unsigned)xA < 48u);
    bool vB = ((unsigned)yB < 48u) && ((unsigned)xB < 48u);
    const unsigned short* baseA2 = Wc2 + (size_t)row0 * 2304 + t * 256 + sslot * 8;
    const unsigned short* base0 = vA ? xT + ((size_t)(b * 2304 + yA * 48 + xA) * 256 + sslot * 8)
                                     : zp + sslot * 8;
    const unsigned short* base1 = vB ? xT + ((size_t)(b * 2304 + yB * 48 + xB) * 256 + sslot * 8)
                                     : zp + sslot * 8;
    #pragma unroll
    for (int cq = 0; cq < 4; cq++) {
      int c0s = cq * 64;
      __syncthreads();                        // prev tile reads done
      gload16(baseA2 + c0s, ldsA + tid * 8);
      gload16(base0  + c0s, ldsB + tid * 8);
      gload16(base1  + c0s, ldsB + 2048 + tid * 8);
      __syncthreads();                        // drain vmcnt + barrier
      #pragma unroll
      for (int ki = 0; ki < 2; ki++) {
        int sl = ((ki * 4 + q) ^ (r & 7)) * 8;
        v8s a0 = *(const v8s*)&ldsA[r * 64 + sl];
        v8s a1 = *(const v8s*)&ldsA[(16 + r) * 64 + sl];
        v8s bb = *(const v8s*)&ldsB[(wid * 16 + r) * 64 + sl];
        acc0 = __builtin_amdgcn_mfma_f32_16x16x32_bf16(a0, bb, acc0, 0, 0, 0);
        acc1 = __builtin_amdgcn_mfma_f32_16x16x32_bf16(a1, bb, acc1, 0, 0, 0);
      }
    }
  }

  float* pp = parS + (size_t)kc * 32 * NPOS + n0;
  #pragma unroll
  for (int e = 0; e < 4; e++) {
    pp[(size_t)(q * 4 + e) * NPOS      + wid * 16 + r] = acc0[e];
    pp[(size_t)(16 + q * 4 + e) * NPOS + wid * 16 + r] = acc1[e];
  }
}

// ---------------- finalize: reduce 3 chunks, bias, sigmoid, coords -----------
// smp layout: [k][pos][{py,px,m}]
__global__ __launch_bounds__(256) void k_fin(const float* __restrict__ parS,
                                             const float* __restrict__ off_b,
                                             const float* __restrict__ mask_b,
                                             float* __restrict__ smp) {
  int k = blockIdx.x / 72;                    // 72 blocks per k (NPOS/256)
  int pos = (blockIdx.x % 72) * 256 + threadIdx.x;
  float s0 = 0.f, s1 = 0.f, s2 = 0.f;
  #pragma unroll
  for (int g = 0; g < 3; g++) {
    const float* pg = parS + (size_t)g * 32 * NPOS + pos;
    s0 += pg[(size_t)(2 * k)     * NPOS];
    s1 += pg[(size_t)(2 * k + 1) * NPOS];
    s2 += pg[(size_t)(18 + k)    * NPOS];
  }
  int hw = pos % 2304; int h = hw / 48, w = hw % 48;
  float m = 1.f / (1.f + expf(-(s2 + mask_b[k])));
  float* sp = smp + ((size_t)k * NPOS + pos) * 3;
  sp[0] = s0 + off_b[2 * k]     + (float)(k / 3) + (float)h - 1.f;
  sp[1] = s1 + off_b[2 * k + 1] + (float)(k % 3) + (float)w - 1.f;
  sp[2] = m;
}

// ---------------- deformable im2col v2: val[pos][k*256+c] bf16 ---------------
// One wave per (pos,tap); lane owns 4 channels; dwordx2 corner loads.
// XCD i owns image i (xT slice 1.2MB L2-resident); full-occupancy TLP.
__global__ __launch_bounds__(256) void k_gather(const unsigned short* __restrict__ xT,
                                                const float* __restrict__ smp,
                                                unsigned short* __restrict__ val) {
  int raw = blockIdx.x;                       // 41472 = 8 img x 5184
  int b = raw & 7;                            // image == XCD
  int it = raw >> 3;                          // 0..5183
  int wv = threadIdx.x >> 6, lane = threadIdx.x & 63;
  int task = it * 4 + wv;                     // 0..20735 within image
  int k = task % 9, hw = task / 9;
  int pos = b * 2304 + hw;
  const float* sp = smp + ((size_t)k * NPOS + pos) * 3;
  float py = sp[0], px = sp[1], m = sp[2];
  float y0f = floorf(py), x0f = floorf(px);
  float wy = py - y0f, wx = px - x0f;
  int y0 = (int)y0f, x0 = (int)x0f;
  bool vy0 = (y0 >= 0) && (y0 <= 47), vy1 = (y0 >= -1) && (y0 <= 46);
  bool vx0 = (x0 >= 0) && (x0 <= 47), vx1 = (x0 >= -1) && (x0 <= 46);
  int yc0 = min(max(y0, 0), 47), yc1 = min(max(y0 + 1, 0), 47);
  int xc0 = min(max(x0, 0), 47), xc1 = min(max(x0 + 1, 0), 47);
  float w00 = (1.f - wy) * (1.f - wx) * m * (float)(vy0 && vx0);
  float w01 = (1.f - wy) * wx         * m * (float)(vy0 && vx1);
  float w10 = wy         * (1.f - wx) * m * (float)(vy1 && vx0);
  float w11 = wy         * wx         * m * (float)(vy1 && vx1);
  const unsigned short* xb = xT + (size_t)b * 2304 * 256;
  int ch = lane * 4;
  v4s c00 = *(const v4s*)&xb[(yc0 * 48 + xc0) * 256 + ch];
  v4s c01 = *(const v4s*)&xb[(yc0 * 48 + xc1) * 256 + ch];
  v4s c10 = *(const v4s*)&xb[(yc1 * 48 + xc0) * 256 + ch];
  v4s c11 = *(const v4s*)&xb[(yc1 * 48 + xc1) * 256 + ch];
  unsigned short o[4];
  #pragma unroll
  for (int i = 0; i < 4; i++) {
    float v = w00 * bf2f((unsigned short)c00[i]) + w01 * bf2f((unsigned short)c01[i])
            + w10 * bf2f((unsigned short)c10[i]) + w11 * bf2f((unsigned short)c11[i]);
    o[i] = f2bf(v);
  }
  *(v4s*)&val[(size_t)pos * 2304 + k * 256 + ch] = *(const v4s*)o;
}

// ---------------- main GEMM v4: A in LDS dbuf, B streamed to REGISTERS -------
// C[co][n] = sum_K wG[co][K] * val[n][K]
// M=256 (2 tiles of 128), N=18432 (288 tiles of 64), K=2304 (36 steps of 64).
// B (val) has zero intra-block reuse -> skip its LDS round-trip entirely:
// fragments load straight from global into VGPRs, prefetched 1 step ahead
// (named cur/nxt arrays, no dynamic indexing). LDS traffic per block-step
// drops 72->48 KB (the R15 limiter). A stays in swizzled LDS dbuf. One
// barrier/step; direct stores; image == XCD.
__global__ __launch_bounds__(256) void k_gemm(const unsigned short* __restrict__ wG,
                                              const unsigned short* __restrict__ val,
                                              float* __restrict__ out) {
  __shared__ unsigned short ldsA[2][128 * 64];   // 2 x 16 KB, swizzled slots
  int raw = blockIdx.x;                       // 576 = 8 xcd x 72
  int xcd = raw & 7, idx = raw >> 3;          // idx 0..71
  int mt = idx & 1;
  int nt = xcd * 36 + (idx >> 1);             // image == xcd
  int co0 = mt * 128, n0 = nt * 64;
  int tid = threadIdx.x, lane = tid & 63, wid = tid >> 6;
  int wm = wid >> 1, wn = wid & 1;            // 2x2 waves, wave tile 64x32
  int r = lane & 15, q = lane >> 4;
  int srow = tid >> 3;                        // staging row 0..31
  int sx = ((tid & 7) ^ (srow & 7)) * 8;      // pre-swizzled source slot

  const unsigned short* Ag = wG + (size_t)(co0 + srow) * 2304 + sx;
  // B fragment base: row n0+wn*32+fn*16+r, col k0+ki*32+q*8 (16B per load)
  const unsigned short* Bg0 = val + (size_t)(n0 + wn * 32 + r) * 2304 + q * 8;
  const unsigned short* Bg1 = Bg0 + (size_t)16 * 2304;   // fn=1 row offset

  #define ASTAGE(bufi, k0_) { \
    _Pragma("unroll") for (int i_ = 0; i_ < 4; i_++) \
      gload16(Ag + (k0_) + (size_t)i_ * 32 * 2304, &ldsA[bufi][i_ * 2048 + tid * 8]); }
  #define BLOAD(dst, k0_) { \
    dst##00 = *(const v8s*)(Bg0 + (k0_));          \
    dst##01 = *(const v8s*)(Bg1 + (k0_));          \
    dst##10 = *(const v8s*)(Bg0 + (k0_) + 32);     \
    dst##11 = *(const v8s*)(Bg1 + (k0_) + 32); }

  v4f acc[4][2];
  #pragma unroll
  for (int i = 0; i < 4; i++)
    #pragma unroll
    for (int j = 0; j < 2; j++) acc[i][j] = (v4f){0.f, 0.f, 0.f, 0.f};

  v8s bc00, bc01, bc10, bc11;                 // current step B frags [ki][fn]
  v8s bn00, bn01, bn10, bn11;                 // next step B frags

  ASTAGE(0, 0);                               // prologue: A tile 0
  BLOAD(bc, 0);                               // B frags step 0
  __syncthreads();                            // vmcnt drained -> buf0 + bc ready

  for (int ks = 0; ks < 36; ks++) {
    int cur = ks & 1;
    if (ks + 1 < 36) {
      ASTAGE(cur ^ 1, (ks + 1) * 64);         // A loads fly under MFMAs
      BLOAD(bn, (ks + 1) * 64);               // B regs for next step
    }
    #pragma unroll
    for (int ki = 0; ki < 2; ki++) {
      int sl = ((ki * 4 + q) ^ (r & 7)) * 8;  // swizzled read slot
      v8s af[4];
      #pragma unroll
      for (int fm = 0; fm < 4; fm++)
        af[fm] = *(const v8s*)&ldsA[cur][(wm * 64 + fm * 16 + r) * 64 + sl];
      v8s b0 = (ki == 0) ? bc00 : bc10;
      v8s b1 = (ki == 0) ? bc01 : bc11;
      #pragma unroll
      for (int fm = 0; fm < 4; fm++) {
        acc[fm][0] = __builtin_amdgcn_mfma_f32_16x16x32_bf16(af[fm], b0, acc[fm][0], 0, 0, 0);
        acc[fm][1] = __builtin_amdgcn_mfma_f32_16x16x32_bf16(af[fm], b1, acc[fm][1], 0, 0, 0);
      }
    }
    bc00 = bn00; bc01 = bn01; bc10 = bn10; bc11 = bn11;
    __syncthreads();                          // one barrier/step (drains vmcnt)
  }

  int bimg = n0 / 2304, hw0 = n0 % 2304;      // BN=64 divides 2304: single image
  float* op = out + (size_t)bimg * (256 * 2304) + hw0;
  #pragma unroll
  for (int fm = 0; fm < 4; fm++) {
    int co = co0 + wm * 64 + fm * 16 + q * 4;
    #pragma unroll
    for (int fn = 0; fn < 2; fn++) {
      int nn = wn * 32 + fn * 16 + r;
      #pragma unroll
      for (int e = 0; e < 4; e++)
        op[(size_t)(co + e) * 2304 + nn] = acc[fm][fn][e];
    }
  }
  #undef ASTAGE
  #undef BLOAD
}

extern "C" void kernel_launch(void* const* d_in, const int* in_sizes, int n_in,
                              void* d_out, int out_size, void* d_ws, size_t ws_size,
                              hipStream_t stream) {
  const float* x      = (const float*)d_in[0];
  const float* weight = (const float*)d_in[1];
  const float* off_w  = (const float*)d_in[2];
  const float* off_b  = (const float*)d_in[3];
  const float* mask_w = (const float*)d_in[4];
  const float* mask_b = (const float*)d_in[5];
  float* out = (float*)d_out;
  char* ws = (char*)d_ws;

  unsigned short* xT   = (unsigned short*)(ws);             //  9,437,184 B -> 9,437,184
  unsigned short* wG   = (unsigned short*)(ws + 9437184);   //  1,179,648 B -> 10,616,832
  unsigned short* Wc2  = (unsigned short*)(ws + 10616832);  //    147,456 B -> 10,764,288
  unsigned short* zp   = (unsigned short*)(ws + 10764288);  //        512 B -> 10,764,800
  float*          smp  = (float*)(ws + 10764800);           //  1,990,656 B -> 12,755,456
  float*          parS = (float*)(ws + 12755456);           //  7,077,888 B -> 19,833,344
  unsigned short* val  = (unsigned short*)(ws + 12755456);  // overlaps parS (dead after k_fin)
                                                            // 84,934,656 B -> 97,690,112

  hipLaunchKernelGGL(k_pre,    dim3(1696),     dim3(256), 0, stream,
                     x, off_w, mask_w, weight, xT, Wc2, zp, wG);
  hipLaunchKernelGGL(k_cg,     dim3(288, 3),   dim3(256), 0, stream, Wc2, xT, zp, parS);
  hipLaunchKernelGGL(k_fin,    dim3(648),      dim3(256), 0, stream, parS, off_b, mask_b, smp);
  hipLaunchKernelGGL(k_gather, dim3(41472),    dim3(256), 0, stream, xT, smp, val);
  hipLaunchKernelGGL(k_gemm,   dim3(576),      dim3(256), 0, stream, wG, val, out);
}

// Round 17
// 83.797 us; speedup vs baseline: 1.5090x; 1.5090x over previous
//
#include <hip/hip_runtime.h>
#include <cstdint>
#include <cmath>

#define DEV __device__ __forceinline__

typedef float v4f __attribute__((ext_vector_type(4)));
typedef short v8s __attribute__((ext_vector_type(8)));
typedef short v4s __attribute__((ext_vector_type(4)));

// Problem constants
// x: [8,256,48,48] f32; weight: [256,256,3,3]; off_w: [18,256,3,3]; off_b:[18];
// mask_w: [9,256,3,3]; mask_b:[9]; out: [8,256,48,48] f32
static constexpr int HW    = 48 * 48;        // 2304
static constexpr int NPOS  = 8 * HW;         // 18432

DEV float bf2f(unsigned short u) {
  unsigned int v = ((unsigned int)u) << 16;
  float f; __builtin_memcpy(&f, &v, 4); return f;
}
DEV unsigned short f2bf(float f) {
  unsigned int u; __builtin_memcpy(&u, &f, 4);
  unsigned int r = (u + 0x7fffu + ((u >> 16) & 1u)) >> 16;
  return (unsigned short)r;
}

DEV void gload16(const void* g, void* l) {
  __builtin_amdgcn_global_load_lds(
      (const __attribute__((address_space(1))) unsigned int*)g,
      (__attribute__((address_space(3))) unsigned int*)l, 16, 0, 0);
}

// ---------------- prep (fused): xT transpose; Wc2+zp; wG ---------------------
// grid 1696 x 256:
//   blocks    0..1151: x NCHW f32 -> xT [b][hw][c] bf16
//   blocks 1152..1439: Wc2[32][t*256+c] bf16 (+ zp zero-page)
//   blocks 1440..1695: wG[co][k*256+c] bf16 row transpose
__global__ __launch_bounds__(256) void k_pre(const float* __restrict__ x,
                                             const float* __restrict__ off_w,
                                             const float* __restrict__ mask_w,
                                             const float* __restrict__ weight,
                                             unsigned short* __restrict__ xT,
                                             unsigned short* __restrict__ Wc2,
                                             unsigned short* __restrict__ zp,
                                             unsigned short* __restrict__ wG) {
  __shared__ float tile[64][65];
  int bid = blockIdx.x, tid = threadIdx.x;
  if (bid < 1152) {
    int ct = bid & 3; int hwt = (bid >> 2) % 36; int b = bid / 144;
    int c0 = ct * 64, hw0 = hwt * 64;
    int tl = tid & 63, tr = tid >> 6;
    const float* xb = x + (size_t)(b * 256 + c0) * 2304 + hw0;
    #pragma unroll
    for (int r = 0; r < 16; r++) {
      int cr = tr + r * 4;
      tile[cr][tl] = xb[(size_t)cr * 2304 + tl];
    }
    __syncthreads();
    unsigned short* xo = xT + ((size_t)b * 2304 + hw0) * 256 + c0;
    #pragma unroll
    for (int r = 0; r < 16; r++) {
      int hr = tr + r * 4;
      xo[(size_t)hr * 256 + tl] = f2bf(tile[tl][hr]);
    }
  } else if (bid < 1440) {
    int i = (bid - 1152) * 256 + tid;         // 288*256 = 73728 = 32*2304
    if (i < 256) zp[i] = 0;
    int o = i / 2304, col = i % 2304;
    int t = col >> 8, c = col & 255;
    float v = 0.f;
    if (o < 18)      v = off_w[(o * 256 + c) * 9 + t];
    else if (o < 27) v = mask_w[((o - 18) * 256 + c) * 9 + t];
    Wc2[i] = f2bf(v);
  } else {
    int co = bid - 1440;
    const float* wsrc = weight + (size_t)co * 2304;
    float* wrow = &tile[0][0];                // reuse 2304 floats of LDS
    for (int k = tid; k < 2304; k += 256) wrow[k] = wsrc[k];
    __syncthreads();
    unsigned short* dst = wG + (size_t)co * 2304;
    #pragma unroll
    for (int k = 0; k < 9; k++)
      dst[k * 256 + tid] = f2bf(wrow[tid * 9 + k]);
  }
}

// ---------------- offset/mask conv as MFMA GEMM ------------------------------
// S[32][NPOS] = Wc2[32][2304] * im2col(xT)[2304][NPOS], split-K by tap triple.
// grid (288, 3): BN=64, per chunk K=768 (3 taps x 256 ch), BK=64.
__global__ __launch_bounds__(256) void k_cg(const unsigned short* __restrict__ Wc2,
                                            const unsigned short* __restrict__ xT,
                                            const unsigned short* __restrict__ zp,
                                            float* __restrict__ parS) {
  __shared__ unsigned short ldsA[32 * 64];
  __shared__ unsigned short ldsB[64 * 64];
  int nt = blockIdx.x, kc = blockIdx.y;
  int n0 = nt * 64;
  int b = n0 / 2304, hw0 = n0 % 2304;         // BN=64 divides 2304: one image
  int tid = threadIdx.x, lane = tid & 63, wid = tid >> 6;
  int r = lane & 15, q = lane >> 4;
  int row0 = tid >> 3;                        // staging row (0..31)
  int sslot = (tid & 7) ^ (row0 & 7);         // pre-swizzled 16B slot

  int hwA = hw0 + row0,      hA = hwA / 48, wA = hwA % 48;   // B round 0 row
  int hwB = hw0 + row0 + 32, hB = hwB / 48, wB = hwB % 48;   // B round 1 row

  v4f acc0 = (v4f){0.f, 0.f, 0.f, 0.f};
  v4f acc1 = (v4f){0.f, 0.f, 0.f, 0.f};

  #pragma unroll
  for (int tt = 0; tt < 3; tt++) {
    int t = kc * 3 + tt;
    int dy = kc - 1, dx = tt - 1;
    int yA = hA + dy, xA = wA + dx;
    int yB = hB + dy, xB = wB + dx;
    bool vA = ((unsigned)yA < 48u) && ((unsigned)xA < 48u);
    bool vB = ((unsigned)yB < 48u) && ((unsigned)xB < 48u);
    const unsigned short* baseA2 = Wc2 + (size_t)row0 * 2304 + t * 256 + sslot * 8;
    const unsigned short* base0 = vA ? xT + ((size_t)(b * 2304 + yA * 48 + xA) * 256 + sslot * 8)
                                     : zp + sslot * 8;
    const unsigned short* base1 = vB ? xT + ((size_t)(b * 2304 + yB * 48 + xB) * 256 + sslot * 8)
                                     : zp + sslot * 8;
    #pragma unroll
    for (int cq = 0; cq < 4; cq++) {
      int c0s = cq * 64;
      __syncthreads();                        // prev tile reads done
      gload16(baseA2 + c0s, ldsA + tid * 8);
      gload16(base0  + c0s, ldsB + tid * 8);
      gload16(base1  + c0s, ldsB + 2048 + tid * 8);
      __syncthreads();                        // drain vmcnt + barrier
      #pragma unroll
      for (int ki = 0; ki < 2; ki++) {
        int sl = ((ki * 4 + q) ^ (r & 7)) * 8;
        v8s a0 = *(const v8s*)&ldsA[r * 64 + sl];
        v8s a1 = *(const v8s*)&ldsA[(16 + r) * 64 + sl];
        v8s bb = *(const v8s*)&ldsB[(wid * 16 + r) * 64 + sl];
        acc0 = __builtin_amdgcn_mfma_f32_16x16x32_bf16(a0, bb, acc0, 0, 0, 0);
        acc1 = __builtin_amdgcn_mfma_f32_16x16x32_bf16(a1, bb, acc1, 0, 0, 0);
      }
    }
  }

  float* pp = parS + (size_t)kc * 32 * NPOS + n0;
  #pragma unroll
  for (int e = 0; e < 4; e++) {
    pp[(size_t)(q * 4 + e) * NPOS      + wid * 16 + r] = acc0[e];
    pp[(size_t)(16 + q * 4 + e) * NPOS + wid * 16 + r] = acc1[e];
  }
}

// ---------------- finalize: reduce 3 chunks, bias, sigmoid, coords -----------
// smp layout: [k][pos][{py,px,m}]
__global__ __launch_bounds__(256) void k_fin(const float* __restrict__ parS,
                                             const float* __restrict__ off_b,
                                             const float* __restrict__ mask_b,
                                             float* __restrict__ smp) {
  int k = blockIdx.x / 72;                    // 72 blocks per k (NPOS/256)
  int pos = (blockIdx.x % 72) * 256 + threadIdx.x;
  float s0 = 0.f, s1 = 0.f, s2 = 0.f;
  #pragma unroll
  for (int g = 0; g < 3; g++) {
    const float* pg = parS + (size_t)g * 32 * NPOS + pos;
    s0 += pg[(size_t)(2 * k)     * NPOS];
    s1 += pg[(size_t)(2 * k + 1) * NPOS];
    s2 += pg[(size_t)(18 + k)    * NPOS];
  }
  int hw = pos % 2304; int h = hw / 48, w = hw % 48;
  float m = 1.f / (1.f + expf(-(s2 + mask_b[k])));
  float* sp = smp + ((size_t)k * NPOS + pos) * 3;
  sp[0] = s0 + off_b[2 * k]     + (float)(k / 3) + (float)h - 1.f;
  sp[1] = s1 + off_b[2 * k + 1] + (float)(k % 3) + (float)w - 1.f;
  sp[2] = m;
}

// ---------------- deformable im2col v3: val[pos][k*256+c] bf16 ---------------
// HALF-WAVE per (pos,tap): lane owns 8 channels -> all corner loads and the
// val store are 16B/lane (coalescing sweet spot); each half-wave reads one
// full 512B xT row per corner. Wave count halves vs v2; TLP still massive
// (20736 blocks). XCD i owns image i (xT slice 1.2MB L2-resident).
__global__ __launch_bounds__(256) void k_gather(const unsigned short* __restrict__ xT,
                                                const float* __restrict__ smp,
                                                unsigned short* __restrict__ val) {
  int raw = blockIdx.x;                       // 20736 = 8 img x 2592
  int b = raw & 7;                            // image == XCD
  int it = raw >> 3;                          // 0..2591
  int half = threadIdx.x >> 5;                // 0..7 (half-wave id in block)
  int lane = threadIdx.x & 31;
  int task = it * 8 + half;                   // 0..20735 within image
  int k = task % 9, hw = task / 9;
  int pos = b * 2304 + hw;
  const float* sp = smp + ((size_t)k * NPOS + pos) * 3;
  float py = sp[0], px = sp[1], m = sp[2];
  float y0f = floorf(py), x0f = floorf(px);
  float wy = py - y0f, wx = px - x0f;
  int y0 = (int)y0f, x0 = (int)x0f;
  bool vy0 = (y0 >= 0) && (y0 <= 47), vy1 = (y0 >= -1) && (y0 <= 46);
  bool vx0 = (x0 >= 0) && (x0 <= 47), vx1 = (x0 >= -1) && (x0 <= 46);
  int yc0 = min(max(y0, 0), 47), yc1 = min(max(y0 + 1, 0), 47);
  int xc0 = min(max(x0, 0), 47), xc1 = min(max(x0 + 1, 0), 47);
  float w00 = (1.f - wy) * (1.f - wx) * m * (float)(vy0 && vx0);
  float w01 = (1.f - wy) * wx         * m * (float)(vy0 && vx1);
  float w10 = wy         * (1.f - wx) * m * (float)(vy1 && vx0);
  float w11 = wy         * wx         * m * (float)(vy1 && vx1);
  const unsigned short* xb = xT + (size_t)b * 2304 * 256;
  int ch = lane * 8;
  v8s c00 = *(const v8s*)&xb[(yc0 * 48 + xc0) * 256 + ch];
  v8s c01 = *(const v8s*)&xb[(yc0 * 48 + xc1) * 256 + ch];
  v8s c10 = *(const v8s*)&xb[(yc1 * 48 + xc0) * 256 + ch];
  v8s c11 = *(const v8s*)&xb[(yc1 * 48 + xc1) * 256 + ch];
  unsigned short o[8];
  #pragma unroll
  for (int i = 0; i < 8; i++) {
    float v = w00 * bf2f((unsigned short)c00[i]) + w01 * bf2f((unsigned short)c01[i])
            + w10 * bf2f((unsigned short)c10[i]) + w11 * bf2f((unsigned short)c11[i]);
    o[i] = f2bf(v);
  }
  *(v8s*)&val[(size_t)pos * 2304 + k * 256 + ch] = *(const v8s*)o;
}

// ---------------- main GEMM v3 (R15, best-known): A+B LDS dbuf ---------------
// C[co][n] = sum_K wG[co][K] * val[n][K]
// M=256 (2 tiles of 128), N=18432 (288 tiles of 64), K=2304 (36 steps of 64).
// Grid 576 = 8 xcd x 72; LDS 48KB dbuf -> 3 blocks/CU. Stage next tile FIRST,
// then compute on current (loads fly under MFMAs), ONE barrier/step. Direct
// stores; both-sides XOR swizzle; image == XCD. (R16 lesson: B-in-registers
// breaks this — reg loads share vmcnt with global_load_lds, so waiting for B
// drains the A prefetch; and the 16-row-scatter B loads uncoalesce.)
__global__ __launch_bounds__(256) void k_gemm(const unsigned short* __restrict__ wG,
                                              const unsigned short* __restrict__ val,
                                              float* __restrict__ out) {
  __shared__ unsigned short ldsA[2][128 * 64];   // 2 x 16 KB, swizzled slots
  __shared__ unsigned short ldsB[2][64 * 64];    // 2 x  8 KB, swizzled slots
  int raw = blockIdx.x;                       // 576 = 8 xcd x 72
  int xcd = raw & 7, idx = raw >> 3;          // idx 0..71
  int mt = idx & 1;
  int nt = xcd * 36 + (idx >> 1);             // image == xcd
  int co0 = mt * 128, n0 = nt * 64;
  int tid = threadIdx.x, lane = tid & 63, wid = tid >> 6;
  int wm = wid >> 1, wn = wid & 1;            // 2x2 waves, wave tile 64x32
  int r = lane & 15, q = lane >> 4;
  int srow = tid >> 3;                        // staging row 0..31
  int sx = ((tid & 7) ^ (srow & 7)) * 8;      // pre-swizzled source slot

  const unsigned short* Ag = wG  + (size_t)(co0 + srow) * 2304 + sx;
  const unsigned short* Bg = val + (size_t)(n0  + srow) * 2304 + sx;

  #define GSTAGE(bufi, k0_) { \
    _Pragma("unroll") for (int i_ = 0; i_ < 4; i_++) \
      gload16(Ag + (k0_) + (size_t)i_ * 32 * 2304, &ldsA[bufi][i_ * 2048 + tid * 8]); \
    _Pragma("unroll") for (int i_ = 0; i_ < 2; i_++) \
      gload16(Bg + (k0_) + (size_t)i_ * 32 * 2304, &ldsB[bufi][i_ * 2048 + tid * 8]); }

  v4f acc[4][2];
  #pragma unroll
  for (int i = 0; i < 4; i++)
    #pragma unroll
    for (int j = 0; j < 2; j++) acc[i][j] = (v4f){0.f, 0.f, 0.f, 0.f};

  GSTAGE(0, 0);                               // prologue: tile 0
  __syncthreads();                            // vmcnt drained -> buf0 ready

  for (int ks = 0; ks < 36; ks++) {
    int cur = ks & 1;
    if (ks + 1 < 36) GSTAGE(cur ^ 1, (ks + 1) * 64);  // loads fly under MFMAs
    #pragma unroll
    for (int ki = 0; ki < 2; ki++) {
      int sl = ((ki * 4 + q) ^ (r & 7)) * 8;  // swizzled read slot
      v8s af[4], bf[2];
      #pragma unroll
      for (int fm = 0; fm < 4; fm++)
        af[fm] = *(const v8s*)&ldsA[cur][(wm * 64 + fm * 16 + r) * 64 + sl];
      #pragma unroll
      for (int fn = 0; fn < 2; fn++)
        bf[fn] = *(const v8s*)&ldsB[cur][(wn * 32 + fn * 16 + r) * 64 + sl];
      #pragma unroll
      for (int fm = 0; fm < 4; fm++)
        #pragma unroll
        for (int fn = 0; fn < 2; fn++)
          acc[fm][fn] = __builtin_amdgcn_mfma_f32_16x16x32_bf16(af[fm], bf[fn], acc[fm][fn], 0, 0, 0);
    }
    __syncthreads();                          // one barrier/step: next buf ready,
  }                                           // and cur buf safe to overwrite

  int bimg = n0 / 2304, hw0 = n0 % 2304;      // BN=64 divides 2304: single image
  float* op = out + (size_t)bimg * (256 * 2304) + hw0;
  #pragma unroll
  for (int fm = 0; fm < 4; fm++) {
    int co = co0 + wm * 64 + fm * 16 + q * 4;
    #pragma unroll
    for (int fn = 0; fn < 2; fn++) {
      int nn = wn * 32 + fn * 16 + r;
      #pragma unroll
      for (int e = 0; e < 4; e++)
        op[(size_t)(co + e) * 2304 + nn] = acc[fm][fn][e];
    }
  }
  #undef GSTAGE
}

extern "C" void kernel_launch(void* const* d_in, const int* in_sizes, int n_in,
                              void* d_out, int out_size, void* d_ws, size_t ws_size,
                              hipStream_t stream) {
  const float* x      = (const float*)d_in[0];
  const float* weight = (const float*)d_in[1];
  const float* off_w  = (const float*)d_in[2];
  const float* off_b  = (const float*)d_in[3];
  const float* mask_w = (const float*)d_in[4];
  const float* mask_b = (const float*)d_in[5];
  float* out = (float*)d_out;
  char* ws = (char*)d_ws;

  unsigned short* xT   = (unsigned short*)(ws);             //  9,437,184 B -> 9,437,184
  unsigned short* wG   = (unsigned short*)(ws + 9437184);   //  1,179,648 B -> 10,616,832
  unsigned short* Wc2  = (unsigned short*)(ws + 10616832);  //    147,456 B -> 10,764,288
  unsigned short* zp   = (unsigned short*)(ws + 10764288);  //        512 B -> 10,764,800
  float*          smp  = (float*)(ws + 10764800);           //  1,990,656 B -> 12,755,456
  float*          parS = (float*)(ws + 12755456);           //  7,077,888 B -> 19,833,344
  unsigned short* val  = (unsigned short*)(ws + 12755456);  // overlaps parS (dead after k_fin)
                                                            // 84,934,656 B -> 97,690,112

  hipLaunchKernelGGL(k_pre,    dim3(1696),     dim3(256), 0, stream,
                     x, off_w, mask_w, weight, xT, Wc2, zp, wG);
  hipLaunchKernelGGL(k_cg,     dim3(288, 3),   dim3(256), 0, stream, Wc2, xT, zp, parS);
  hipLaunchKernelGGL(k_fin,    dim3(648),      dim3(256), 0, stream, parS, off_b, mask_b, smp);
  hipLaunchKernelGGL(k_gather, dim3(20736),    dim3(256), 0, stream, xT, smp, val);
  hipLaunchKernelGGL(k_gemm,   dim3(576),      dim3(256), 0, stream, wG, val, out);
}